// Round 4
// baseline (2891.092 us; speedup 1.0000x reference)
//
#include <hip/hip_runtime.h>
#include <math.h>

#define NE 32
#define HID 2880
#define TT 64            // tokens per block
#define THREADS 1024     // 16 waves
#define CK 192           // k-chunk width staged in LDS
#define NCHUNK 15        // 2880 / 192
#define WS 12            // k per wave per chunk (CK/16)
#define RS 192           // hbuf row stride in floats

// global_load_lds: wave-uniform LDS dest + lane*16; per-lane global src.
#define GLL(gsrc, ldst)                                                        \
  __builtin_amdgcn_global_load_lds(                                            \
      (const __attribute__((address_space(1))) unsigned int*)(gsrc),           \
      (__attribute__((address_space(3))) unsigned int*)(ldst), 16, 0, 0)

__global__ void __launch_bounds__(THREADS) router_gemm(
    const float* __restrict__ hs,     // [T][HID]
    const float* __restrict__ w,      // [NE][HID]
    const float* __restrict__ bias,   // [NE]
    float* __restrict__ out,          // [T][NE] scores, then [T][4] idx-as-float
    int T)
{
  __shared__ float hbuf0[TT * RS];    // 49152 B  (h chunk, double-buffered)
  __shared__ float hbuf1[TT * RS];    // 49152 B
  __shared__ float wbuf[NE * CK];     // 24576 B  (W chunk, [e][192] linear)
  __shared__ float part[4][TT][36];   // 36864 B  -> total 159744 B

  const int tid  = threadIdx.x;
  const int wv   = __builtin_amdgcn_readfirstlane(tid >> 6);
  const int lane = tid & 63;
  const int t0   = blockIdx.x * TT;

  // ---- precomputed source offsets (chunk-independent) ----
  // h staging: LDS slot f holds h[row][ (f%48) ^ (row&7) ]  (XOR swizzle via
  // pre-swizzled GLOBAL source; LDS dest stays linear for global_load_lds).
  int goffH[3];
#pragma unroll
  for (int i = 0; i < 3; ++i) {
    int f   = (wv * 3 + i) * 64 + lane;
    int row = f / 48;
    int s   = f % 48;
    int col = s ^ (row & 7);
    goffH[i] = row * HID + col * 4;     // float offset
  }
  // W staging: slot f (float4) of wbuf = W[f/48][ (f%48)*4 .. ] of the chunk
  const int goffW0 = (tid / 48) * HID + (tid % 48) * 4;
  const int f1     = 1024 + tid;
  const int goffW1 = (f1 / 48) * HID + (f1 % 48) * 4;

  float acc[NE];
#pragma unroll
  for (int e = 0; e < NE; ++e) acc[e] = 0.f;

  // ---- prologue: stage h(0) (async) and W(0) ----
  {
    const float* src0 = hs + (size_t)t0 * HID;
#pragma unroll
    for (int i = 0; i < 3; ++i)
      GLL(src0 + goffH[i], (char*)hbuf0 + ((wv * 3 + i) << 10));
  }
  float4 ws0 = *(const float4*)(w + goffW0);
  float4 ws1;
  if (wv < 8) ws1 = *(const float4*)(w + goffW1);
  __syncthreads();                       // drains vmcnt: h(0) in LDS, ws in regs
  *(float4*)(wbuf + tid * 4) = ws0;
  if (wv < 8) *(float4*)(wbuf + 4096 + tid * 4) = ws1;
  __syncthreads();

  for (int c = 0; c < NCHUNK; ++c) {
    const float* hb_c = (c & 1) ? hbuf1 : hbuf0;
    float*       hb_n = (c & 1) ? hbuf0 : hbuf1;

    // ---- issue next chunk's staging (async h via GLL; W into regs) ----
    if (c + 1 < NCHUNK) {
      const float* srcn = hs + (size_t)t0 * HID + (c + 1) * CK;
#pragma unroll
      for (int i = 0; i < 3; ++i)
        GLL(srcn + goffH[i], (char*)hb_n + ((wv * 3 + i) << 10));
      ws0 = *(const float4*)(w + (c + 1) * CK + goffW0);
      if (wv < 8) ws1 = *(const float4*)(w + (c + 1) * CK + goffW1);
    }

    // ---- compute chunk c: wave wv owns k-slice [wv*12, +12) ----
    float hreg[WS];
#pragma unroll
    for (int j = 0; j < 3; ++j) {
      float4 hv = *(const float4*)(hb_c + lane * RS + 4 * ((wv * 3 + j) ^ (lane & 7)));
      hreg[j * 4 + 0] = hv.x;
      hreg[j * 4 + 1] = hv.y;
      hreg[j * 4 + 2] = hv.z;
      hreg[j * 4 + 3] = hv.w;
    }
    const float* wub = wbuf + wv * WS;   // wave-uniform -> broadcast ds_read
#pragma unroll
    for (int e = 0; e < NE; ++e) {
      float4 w0 = *(const float4*)(wub + e * CK);
      float4 w1 = *(const float4*)(wub + e * CK + 4);
      float4 w2 = *(const float4*)(wub + e * CK + 8);
      acc[e] = fmaf(hreg[0],  w0.x, acc[e]);
      acc[e] = fmaf(hreg[1],  w0.y, acc[e]);
      acc[e] = fmaf(hreg[2],  w0.z, acc[e]);
      acc[e] = fmaf(hreg[3],  w0.w, acc[e]);
      acc[e] = fmaf(hreg[4],  w1.x, acc[e]);
      acc[e] = fmaf(hreg[5],  w1.y, acc[e]);
      acc[e] = fmaf(hreg[6],  w1.z, acc[e]);
      acc[e] = fmaf(hreg[7],  w1.w, acc[e]);
      acc[e] = fmaf(hreg[8],  w2.x, acc[e]);
      acc[e] = fmaf(hreg[9],  w2.y, acc[e]);
      acc[e] = fmaf(hreg[10], w2.z, acc[e]);
      acc[e] = fmaf(hreg[11], w2.w, acc[e]);
    }
    __syncthreads();                     // readers done; vmcnt drained (h,W next ready)
    if (c + 1 < NCHUNK) {
      *(float4*)(wbuf + tid * 4) = ws0;
      if (wv < 8) *(float4*)(wbuf + 4096 + tid * 4) = ws1;
    }
    __syncthreads();                     // next W visible
  }

  // ---- reduce 16 waves -> part[4] in 4 phases ----
  const int q = wv & 3, p = wv >> 2;
#pragma unroll
  for (int ph = 0; ph < 4; ++ph) {
    if (p == ph) {
      if (ph == 0) {
#pragma unroll
        for (int e = 0; e < NE; e += 4) {
          float4 v;
          v.x = acc[e]; v.y = acc[e + 1]; v.z = acc[e + 2]; v.w = acc[e + 3];
          *(float4*)(&part[q][lane][e]) = v;
        }
      } else {
#pragma unroll
        for (int e = 0; e < NE; e += 4) {
          float4 v = *(float4*)(&part[q][lane][e]);
          v.x += acc[e]; v.y += acc[e + 1]; v.z += acc[e + 2]; v.w += acc[e + 3];
          *(float4*)(&part[q][lane][e]) = v;
        }
      }
    }
    __syncthreads();
  }

  // ---- wave 0: logits = sum(part) + bias; top-4; softmax; scatter ----
  if (wv == 0) {
    float lg[NE];
#pragma unroll
    for (int e = 0; e < NE; e += 4) {
      float4 a  = *(float4*)(&part[0][lane][e]);
      float4 b  = *(float4*)(&part[1][lane][e]);
      float4 cc = *(float4*)(&part[2][lane][e]);
      float4 d  = *(float4*)(&part[3][lane][e]);
      float4 bb = *(const float4*)(bias + e);
      lg[e]     = a.x + b.x + cc.x + d.x + bb.x;
      lg[e + 1] = a.y + b.y + cc.y + d.y + bb.y;
      lg[e + 2] = a.z + b.z + cc.z + d.z + bb.z;
      lg[e + 3] = a.w + b.w + cc.w + d.w + bb.w;
    }

    float tv[4]; int ti[4];
#pragma unroll
    for (int kk = 0; kk < 4; ++kk) {
      float m = -INFINITY; int mi = 0;
#pragma unroll
      for (int e = 0; e < NE; ++e) {
        bool gt = lg[e] > m;      // strict >: lowest index wins ties (jax semantics)
        m  = gt ? lg[e] : m;
        mi = gt ? e : mi;
      }
      tv[kk] = m; ti[kk] = mi;
#pragma unroll
      for (int e = 0; e < NE; ++e)
        lg[e] = (e == mi) ? -INFINITY : lg[e];
    }

    float e1 = __expf(tv[1] - tv[0]);
    float e2 = __expf(tv[2] - tv[0]);
    float e3 = __expf(tv[3] - tv[0]);
    float inv = 1.0f / (1.0f + e1 + e2 + e3);
    float pr[4] = {inv, e1 * inv, e2 * inv, e3 * inv};

    const int tok = t0 + lane;
    float* orow = out + (size_t)tok * NE;
#pragma unroll
    for (int g = 0; g < 8; ++g) {
      float4 v;
      float* vp = (float*)&v;
#pragma unroll
      for (int cb = 0; cb < 4; ++cb) {
        int e = g * 4 + cb;
        float x = 0.f;
        x = (e == ti[0]) ? pr[0] : x;
        x = (e == ti[1]) ? pr[1] : x;
        x = (e == ti[2]) ? pr[2] : x;
        x = (e == ti[3]) ? pr[3] : x;
        vp[cb] = x;
      }
      *(float4*)(orow + g * 4) = v;
    }
    float* oidx = out + (size_t)T * NE + (size_t)tok * 4;
    float4 iv;
    iv.x = (float)ti[0]; iv.y = (float)ti[1]; iv.z = (float)ti[2]; iv.w = (float)ti[3];
    *(float4*)oidx = iv;
  }
}

extern "C" void kernel_launch(void* const* d_in, const int* in_sizes, int n_in,
                              void* d_out, int out_size, void* d_ws, size_t ws_size,
                              hipStream_t stream) {
  const float* hs   = (const float*)d_in[0];
  const float* w    = (const float*)d_in[1];
  const float* bias = (const float*)d_in[2];
  float* out        = (float*)d_out;

  const int T = in_sizes[0] / HID;   // 16384
  const int blocks = T / TT;         // 256

  hipLaunchKernelGGL(router_gemm, dim3(blocks), dim3(THREADS), 0, stream,
                     hs, w, bias, out, T);
}

// Round 5
// 99.183 us; speedup vs baseline: 29.1490x; 29.1490x over previous
//
#include <hip/hip_runtime.h>
#include <math.h>

#define NE 32
#define HID 2880
#define TT 64            // tokens per block
#define THREADS 1024     // 16 waves = 2 (expert-half) x 8 (k-slice)
#define CK 192           // k-chunk staged in LDS
#define NCHUNK 15        // 2880 / 192
#define RS 192           // hbuf row stride (floats)

typedef float f32x8 __attribute__((ext_vector_type(8)));

// global_load_lds: wave-uniform LDS dest + lane*16; per-lane global src.
#define GLL(gsrc, ldst)                                                        \
  __builtin_amdgcn_global_load_lds(                                            \
      (const __attribute__((address_space(1))) unsigned int*)(gsrc),           \
      (__attribute__((address_space(3))) unsigned int*)(ldst), 16, 0, 0)

// Issue 3 scalar loads (24 floats = one expert's k-slice) into SGPRs.
#define WISSUE(b0, b1, b2, O0, O1, O2)                                         \
  asm volatile("s_load_dwordx8 %0, %3, " O0 "\n\t"                             \
               "s_load_dwordx8 %1, %3, " O1 "\n\t"                             \
               "s_load_dwordx8 %2, %3, " O2                                    \
               : "=&s"(b0), "=&s"(b1), "=&s"(b2)                               \
               : "s"(wbase)                                                    \
               : "memory");

// Wait for SMEM (unordered completion -> lgkmcnt(0) only); tie buffers to the
// wait so FMAs can't be hoisted above it (rule #18), then fence the scheduler.
#define WWAIT(b0, b1, b2)                                                      \
  asm volatile("s_waitcnt lgkmcnt(0)"                                          \
               : "+s"(b0), "+s"(b1), "+s"(b2)::"memory");                      \
  __builtin_amdgcn_sched_barrier(0);

// 24 FMAs for expert i: 3 independent 8-chains (hides v_fmac latency).
#define WFMA(i, b0, b1, b2)                                                    \
  {                                                                            \
    float t0 = fmaf(hreg[0], b0.s0, acc[i]);                                   \
    t0 = fmaf(hreg[1], b0.s1, t0);                                             \
    t0 = fmaf(hreg[2], b0.s2, t0);                                             \
    t0 = fmaf(hreg[3], b0.s3, t0);                                             \
    t0 = fmaf(hreg[4], b0.s4, t0);                                             \
    t0 = fmaf(hreg[5], b0.s5, t0);                                             \
    t0 = fmaf(hreg[6], b0.s6, t0);                                             \
    t0 = fmaf(hreg[7], b0.s7, t0);                                             \
    float t1 = hreg[8] * b1.s0;                                                \
    t1 = fmaf(hreg[9], b1.s1, t1);                                             \
    t1 = fmaf(hreg[10], b1.s2, t1);                                            \
    t1 = fmaf(hreg[11], b1.s3, t1);                                            \
    t1 = fmaf(hreg[12], b1.s4, t1);                                            \
    t1 = fmaf(hreg[13], b1.s5, t1);                                            \
    t1 = fmaf(hreg[14], b1.s6, t1);                                            \
    t1 = fmaf(hreg[15], b1.s7, t1);                                            \
    float t2 = hreg[16] * b2.s0;                                               \
    t2 = fmaf(hreg[17], b2.s1, t2);                                            \
    t2 = fmaf(hreg[18], b2.s2, t2);                                            \
    t2 = fmaf(hreg[19], b2.s3, t2);                                            \
    t2 = fmaf(hreg[20], b2.s4, t2);                                            \
    t2 = fmaf(hreg[21], b2.s5, t2);                                            \
    t2 = fmaf(hreg[22], b2.s6, t2);                                            \
    t2 = fmaf(hreg[23], b2.s7, t2);                                            \
    acc[i] = t0 + (t1 + t2);                                                   \
  }

__global__ void __launch_bounds__(THREADS) router_gemm(
    const float* __restrict__ hs,     // [T][HID]
    const float* __restrict__ w,      // [NE][HID]
    const float* __restrict__ bias,   // [NE]
    float* __restrict__ out,          // [T][NE] scores, then [T][4] idx-as-float
    int T)
{
  __shared__ float hbuf0[TT * RS];    // 49152 B (h chunk, double-buffered)
  __shared__ float hbuf1[TT * RS];    // 49152 B
  __shared__ float part[2][TT][20];   // 10240 B  -> total 108544 B

  const int tid  = threadIdx.x;
  const int wv   = __builtin_amdgcn_readfirstlane(tid >> 6);
  const int lane = tid & 63;
  const int eg   = wv >> 3;           // expert half: experts [eg*16, +16)
  const int kg   = wv & 7;            // k-slice within chunk: [kg*24, +24)
  const int t0   = blockIdx.x * TT;

  // ---- h staging offsets (validated in round 4): slot f holds
  // h[row][(f%48) ^ (row&7)] via pre-swizzled GLOBAL src, linear LDS dest ----
  int goffH[3];
#pragma unroll
  for (int i = 0; i < 3; ++i) {
    int f   = (wv * 3 + i) * 64 + lane;
    int row = f / 48;
    int s   = f % 48;
    int col = s ^ (row & 7);
    goffH[i] = row * HID + col * 4;   // float offset within chunk
  }

  float acc[16];
#pragma unroll
  for (int i = 0; i < 16; ++i) acc[i] = 0.f;

  // ---- prologue: stage chunk 0 ----
  {
    const float* src0 = hs + (size_t)t0 * HID;
#pragma unroll
    for (int i = 0; i < 3; ++i)
      GLL(src0 + goffH[i], (char*)hbuf0 + ((wv * 3 + i) << 10));
  }
  __syncthreads();   // compiler drains vmcnt before s_barrier

#pragma clang loop unroll(disable)
  for (int c = 0; c < NCHUNK; ++c) {
    const float* hb_c = (c & 1) ? hbuf1 : hbuf0;
    float*       hb_n = (c & 1) ? hbuf0 : hbuf1;

    // issue next chunk's staging (async, vmcnt-tracked; not touched by lgkm waits)
    if (c + 1 < NCHUNK) {
      const float* srcn = hs + (size_t)t0 * HID + (c + 1) * CK;
#pragma unroll
      for (int i = 0; i < 3; ++i)
        GLL(srcn + goffH[i], (char*)hb_n + ((wv * 3 + i) << 10));
    }

    // wave-uniform W base for this (eg, kg, c): experts stride 11520 B in imm
    const float* wbase = w + eg * (16 * HID) + c * CK + kg * 24;

    f32x8 A0, A1, A2, B0, B1, B2;
    WISSUE(A0, A1, A2, "0", "32", "64");          // expert 0 (covers h-read time)

    // ---- h fragment: 24 floats (6 x b128, bank-sweep conflict-free) ----
    float hreg[24];
#pragma unroll
    for (int j4 = 0; j4 < 6; ++j4) {
      int c4 = kg * 6 + j4;
      float4 hv = *(const float4*)(hb_c + lane * RS + 4 * (c4 ^ (lane & 7)));
      hreg[j4 * 4 + 0] = hv.x;
      hreg[j4 * 4 + 1] = hv.y;
      hreg[j4 * 4 + 2] = hv.z;
      hreg[j4 * 4 + 3] = hv.w;
    }

    // ---- 16 experts: wait(cur) / issue(next) / FMA(cur), A-B alternating ----
    WWAIT(A0, A1, A2); WISSUE(B0, B1, B2, "11520", "11552", "11584");   WFMA(0,  A0, A1, A2);
    WWAIT(B0, B1, B2); WISSUE(A0, A1, A2, "23040", "23072", "23104");   WFMA(1,  B0, B1, B2);
    WWAIT(A0, A1, A2); WISSUE(B0, B1, B2, "34560", "34592", "34624");   WFMA(2,  A0, A1, A2);
    WWAIT(B0, B1, B2); WISSUE(A0, A1, A2, "46080", "46112", "46144");   WFMA(3,  B0, B1, B2);
    WWAIT(A0, A1, A2); WISSUE(B0, B1, B2, "57600", "57632", "57664");   WFMA(4,  A0, A1, A2);
    WWAIT(B0, B1, B2); WISSUE(A0, A1, A2, "69120", "69152", "69184");   WFMA(5,  B0, B1, B2);
    WWAIT(A0, A1, A2); WISSUE(B0, B1, B2, "80640", "80672", "80704");   WFMA(6,  A0, A1, A2);
    WWAIT(B0, B1, B2); WISSUE(A0, A1, A2, "92160", "92192", "92224");   WFMA(7,  B0, B1, B2);
    WWAIT(A0, A1, A2); WISSUE(B0, B1, B2, "103680", "103712", "103744"); WFMA(8,  A0, A1, A2);
    WWAIT(B0, B1, B2); WISSUE(A0, A1, A2, "115200", "115232", "115264"); WFMA(9,  B0, B1, B2);
    WWAIT(A0, A1, A2); WISSUE(B0, B1, B2, "126720", "126752", "126784"); WFMA(10, A0, A1, A2);
    WWAIT(B0, B1, B2); WISSUE(A0, A1, A2, "138240", "138272", "138304"); WFMA(11, B0, B1, B2);
    WWAIT(A0, A1, A2); WISSUE(B0, B1, B2, "149760", "149792", "149824"); WFMA(12, A0, A1, A2);
    WWAIT(B0, B1, B2); WISSUE(A0, A1, A2, "161280", "161312", "161344"); WFMA(13, B0, B1, B2);
    WWAIT(A0, A1, A2); WISSUE(B0, B1, B2, "172800", "172832", "172864"); WFMA(14, A0, A1, A2);
    WWAIT(B0, B1, B2);                                                   WFMA(15, B0, B1, B2);

    __syncthreads();   // drains vmcnt (next chunk staged) + lgkm; flips buffers
  }

  // ---- reduce 8 kg-waves per eg-plane: 8 phases ----
#pragma unroll
  for (int ph = 0; ph < 8; ++ph) {
    if (kg == ph) {
      float* pp = &part[eg][lane][0];
      if (ph == 0) {
#pragma unroll
        for (int q = 0; q < 4; ++q) {
          float4 v;
          v.x = acc[q * 4 + 0]; v.y = acc[q * 4 + 1];
          v.z = acc[q * 4 + 2]; v.w = acc[q * 4 + 3];
          *(float4*)(pp + q * 4) = v;
        }
      } else {
#pragma unroll
        for (int q = 0; q < 4; ++q) {
          float4 v = *(float4*)(pp + q * 4);
          v.x += acc[q * 4 + 0]; v.y += acc[q * 4 + 1];
          v.z += acc[q * 4 + 2]; v.w += acc[q * 4 + 3];
          *(float4*)(pp + q * 4) = v;
        }
      }
    }
    __syncthreads();
  }

  // ---- wave 0: logits + bias; top-4; softmax; scatter (validated) ----
  if (wv == 0) {
    float lg[NE];
#pragma unroll
    for (int eg2 = 0; eg2 < 2; ++eg2) {
#pragma unroll
      for (int q = 0; q < 4; ++q) {
        float4 v  = *(float4*)(&part[eg2][lane][q * 4]);
        float4 bb = *(const float4*)(bias + eg2 * 16 + q * 4);
        lg[eg2 * 16 + q * 4 + 0] = v.x + bb.x;
        lg[eg2 * 16 + q * 4 + 1] = v.y + bb.y;
        lg[eg2 * 16 + q * 4 + 2] = v.z + bb.z;
        lg[eg2 * 16 + q * 4 + 3] = v.w + bb.w;
      }
    }

    float tv[4]; int ti[4];
#pragma unroll
    for (int kk = 0; kk < 4; ++kk) {
      float m = -INFINITY; int mi = 0;
#pragma unroll
      for (int e = 0; e < NE; ++e) {
        bool gt = lg[e] > m;      // strict >: lowest index wins ties (jax)
        m  = gt ? lg[e] : m;
        mi = gt ? e : mi;
      }
      tv[kk] = m; ti[kk] = mi;
#pragma unroll
      for (int e = 0; e < NE; ++e)
        lg[e] = (e == mi) ? -INFINITY : lg[e];
    }

    float e1 = __expf(tv[1] - tv[0]);
    float e2 = __expf(tv[2] - tv[0]);
    float e3 = __expf(tv[3] - tv[0]);
    float inv = 1.0f / (1.0f + e1 + e2 + e3);
    float pr[4] = {inv, e1 * inv, e2 * inv, e3 * inv};

    const int tok = t0 + lane;
    float* orow = out + (size_t)tok * NE;
#pragma unroll
    for (int g = 0; g < 8; ++g) {
      float4 v;
      float* vp = (float*)&v;
#pragma unroll
      for (int cb = 0; cb < 4; ++cb) {
        int e = g * 4 + cb;
        float x = 0.f;
        x = (e == ti[0]) ? pr[0] : x;
        x = (e == ti[1]) ? pr[1] : x;
        x = (e == ti[2]) ? pr[2] : x;
        x = (e == ti[3]) ? pr[3] : x;
        vp[cb] = x;
      }
      *(float4*)(orow + g * 4) = v;
    }
    float* oidx = out + (size_t)T * NE + (size_t)tok * 4;
    float4 iv;
    iv.x = (float)ti[0]; iv.y = (float)ti[1]; iv.z = (float)ti[2]; iv.w = (float)ti[3];
    *(float4*)oidx = iv;
  }
}

extern "C" void kernel_launch(void* const* d_in, const int* in_sizes, int n_in,
                              void* d_out, int out_size, void* d_ws, size_t ws_size,
                              hipStream_t stream) {
  const float* hs   = (const float*)d_in[0];
  const float* w    = (const float*)d_in[1];
  const float* bias = (const float*)d_in[2];
  float* out        = (float*)d_out;

  const int T = in_sizes[0] / HID;   // 16384
  const int blocks = T / TT;         // 256

  hipLaunchKernelGGL(router_gemm, dim3(blocks), dim3(THREADS), 0, stream,
                     hs, w, bias, out, T);
}

// Round 6
// 89.294 us; speedup vs baseline: 32.3772x; 1.1107x over previous
//
#include <hip/hip_runtime.h>
#include <math.h>

#define NE 32
#define HID 2880
#define TT 64            // tokens per block (lane = token)
#define THREADS 1024     // 16 waves = 2 (expert-half) x 8 (k-slice)
#define CK 96            // k-chunk staged in LDS
#define NCHUNK 30        // 2880 / 96
#define RS 96            // hbuf row stride (floats)

// global_load_lds: wave-uniform LDS dest + lane*16; per-lane global src.
#define GLL(gsrc, ldst)                                                        \
  __builtin_amdgcn_global_load_lds(                                            \
      (const __attribute__((address_space(1))) unsigned int*)(gsrc),           \
      (__attribute__((address_space(3))) unsigned int*)(ldst), 16, 0, 0)

__global__ void __launch_bounds__(THREADS) router_gemm(
    const float* __restrict__ hs,     // [T][HID]
    const float* __restrict__ w,      // [NE][HID]
    const float* __restrict__ bias,   // [NE]
    float* __restrict__ out,          // [T][NE] scores, then [T][4] idx-as-float
    int T)
{
  // hbuf: [2][64 rows][24 float4-slots]; slot s of row r holds col s^(r&7).
  // wbuf: [2][32 experts][96 floats] linear (broadcast reads: no swizzle).
  __shared__ float hbuf[2][TT * RS];      // 2 x 24576 B
  __shared__ float wbuf[2][NE * CK];      // 2 x 12288 B   -> total 73728 B
  float* const part = &hbuf[0][0];        // [2][64][20] overlay, used after loop

  const int tid  = threadIdx.x;
  const int wv   = __builtin_amdgcn_readfirstlane(tid >> 6);
  const int lane = tid & 63;
  const int eg   = wv >> 3;               // experts [eg*16, +16)
  const int kg   = wv & 7;                // k-slice [kg*12, +12) within chunk
  const int t0   = blockIdx.x * TT;

  // ---- h staging offsets: slot f (16B) <- h[f/24][ ((f%24)^(row&7))*4 ] ----
  int goffH[2];
#pragma unroll
  for (int i = 0; i < 2; ++i) {
    int f   = tid + 1024 * i;             // i=1 only valid for tid<512
    int row = f / 24;
    int s   = f % 24;
    int col = s ^ (row & 7);
    goffH[i] = row * HID + col * 4;       // float offset within chunk
  }
  // ---- W staging offset: slot f (16B, f<768) <- w[f/24][(f%24)*4] ----
  const int goffW = (tid / 24) * HID + (tid % 24) * 4;

  float acc[16];
#pragma unroll
  for (int i = 0; i < 16; ++i) acc[i] = 0.f;

  // ---- prologue: stage chunk 0 ----
  {
    const float* hsrc = hs + (size_t)t0 * HID;
    GLL(hsrc + goffH[0], (char*)&hbuf[0][0] + tid * 16);
    if (tid < 512) GLL(hsrc + goffH[1], (char*)&hbuf[0][0] + 16384 + tid * 16);
    if (tid < 768) GLL(w + goffW, (char*)&wbuf[0][0] + tid * 16);
  }
  __syncthreads();    // compiler drains vmcnt before s_barrier

#pragma clang loop unroll(disable)
  for (int c = 0; c < NCHUNK; ++c) {
    const float* hb_c = &hbuf[c & 1][0];
    const float* wb_c = &wbuf[c & 1][0];

    // issue next chunk's staging (async; lands before next barrier's vmcnt drain)
    if (c + 1 < NCHUNK) {
      char* hb_n = (char*)&hbuf[(c + 1) & 1][0];
      char* wb_n = (char*)&wbuf[(c + 1) & 1][0];
      const float* hsrc = hs + (size_t)t0 * HID + (c + 1) * CK;
      GLL(hsrc + goffH[0], hb_n + tid * 16);
      if (tid < 512) GLL(hsrc + goffH[1], hb_n + 16384 + tid * 16);
      if (tid < 768) GLL(w + (c + 1) * CK + goffW, wb_n + tid * 16);
    }

    // ---- h fragment: 12 floats (3 x b128, swizzled) ----
    float hreg[12];
#pragma unroll
    for (int j = 0; j < 3; ++j) {
      float4 hv = *(const float4*)(hb_c + lane * RS + 4 * ((kg * 3 + j) ^ (lane & 7)));
      hreg[j * 4 + 0] = hv.x;
      hreg[j * 4 + 1] = hv.y;
      hreg[j * 4 + 2] = hv.z;
      hreg[j * 4 + 3] = hv.w;
    }

    // ---- 16 experts x 12 FMAs; W via wave-uniform broadcast ds_read_b128
    //      (imm offsets; DS in-order -> compiler pipelines with counted lgkmcnt)
    const float* wub = wb_c + eg * (16 * CK) + kg * 12;
#pragma unroll
    for (int e = 0; e < 16; ++e) {
      float4 w0 = *(const float4*)(wub + e * CK);
      float4 w1 = *(const float4*)(wub + e * CK + 4);
      float4 w2 = *(const float4*)(wub + e * CK + 8);
      float t0a = fmaf(hreg[0], w0.x, acc[e]);
      t0a = fmaf(hreg[1], w0.y, t0a);
      t0a = fmaf(hreg[2], w0.z, t0a);
      t0a = fmaf(hreg[3], w0.w, t0a);
      float t1a = hreg[4] * w1.x;
      t1a = fmaf(hreg[5], w1.y, t1a);
      t1a = fmaf(hreg[6], w1.z, t1a);
      t1a = fmaf(hreg[7], w1.w, t1a);
      float t2a = hreg[8] * w2.x;
      t2a = fmaf(hreg[9], w2.y, t2a);
      t2a = fmaf(hreg[10], w2.z, t2a);
      t2a = fmaf(hreg[11], w2.w, t2a);
      acc[e] = t0a + (t1a + t2a);
    }

    __syncthreads();  // readers done with c; vmcnt drained (c+1 staged)
  }

  // ---- reduce 8 kg-waves per eg-plane into part overlay: 8 phases ----
#pragma unroll
  for (int ph = 0; ph < 8; ++ph) {
    if (kg == ph) {
      float* pp = part + eg * (TT * 20) + lane * 20;
      if (ph == 0) {
#pragma unroll
        for (int q = 0; q < 4; ++q) {
          float4 v;
          v.x = acc[q * 4 + 0]; v.y = acc[q * 4 + 1];
          v.z = acc[q * 4 + 2]; v.w = acc[q * 4 + 3];
          *(float4*)(pp + q * 4) = v;
        }
      } else {
#pragma unroll
        for (int q = 0; q < 4; ++q) {
          float4 v = *(float4*)(pp + q * 4);
          v.x += acc[q * 4 + 0]; v.y += acc[q * 4 + 1];
          v.z += acc[q * 4 + 2]; v.w += acc[q * 4 + 3];
          *(float4*)(pp + q * 4) = v;
        }
      }
    }
    __syncthreads();
  }

  // ---- wave 0: logits + bias; top-4; softmax; scatter ----
  if (wv == 0) {
    float lg[NE];
#pragma unroll
    for (int eg2 = 0; eg2 < 2; ++eg2) {
#pragma unroll
      for (int q = 0; q < 4; ++q) {
        float4 v  = *(float4*)(part + eg2 * (TT * 20) + lane * 20 + q * 4);
        float4 bb = *(const float4*)(bias + eg2 * 16 + q * 4);
        lg[eg2 * 16 + q * 4 + 0] = v.x + bb.x;
        lg[eg2 * 16 + q * 4 + 1] = v.y + bb.y;
        lg[eg2 * 16 + q * 4 + 2] = v.z + bb.z;
        lg[eg2 * 16 + q * 4 + 3] = v.w + bb.w;
      }
    }

    float tv[4]; int ti[4];
#pragma unroll
    for (int kk = 0; kk < 4; ++kk) {
      float m = -INFINITY; int mi = 0;
#pragma unroll
      for (int e = 0; e < NE; ++e) {
        bool gt = lg[e] > m;      // strict >: lowest index wins ties (jax)
        m  = gt ? lg[e] : m;
        mi = gt ? e : mi;
      }
      tv[kk] = m; ti[kk] = mi;
#pragma unroll
      for (int e = 0; e < NE; ++e)
        lg[e] = (e == mi) ? -INFINITY : lg[e];
    }

    float e1 = __expf(tv[1] - tv[0]);
    float e2 = __expf(tv[2] - tv[0]);
    float e3 = __expf(tv[3] - tv[0]);
    float inv = 1.0f / (1.0f + e1 + e2 + e3);
    float pr[4] = {inv, e1 * inv, e2 * inv, e3 * inv};

    const int tok = t0 + lane;
    float* orow = out + (size_t)tok * NE;
#pragma unroll
    for (int g = 0; g < 8; ++g) {
      float4 v;
      float* vp = (float*)&v;
#pragma unroll
      for (int cb = 0; cb < 4; ++cb) {
        int e = g * 4 + cb;
        float x = 0.f;
        x = (e == ti[0]) ? pr[0] : x;
        x = (e == ti[1]) ? pr[1] : x;
        x = (e == ti[2]) ? pr[2] : x;
        x = (e == ti[3]) ? pr[3] : x;
        vp[cb] = x;
      }
      *(float4*)(orow + g * 4) = v;
    }
    float* oidx = out + (size_t)T * NE + (size_t)tok * 4;
    float4 iv;
    iv.x = (float)ti[0]; iv.y = (float)ti[1]; iv.z = (float)ti[2]; iv.w = (float)ti[3];
    *(float4*)oidx = iv;
  }
}

extern "C" void kernel_launch(void* const* d_in, const int* in_sizes, int n_in,
                              void* d_out, int out_size, void* d_ws, size_t ws_size,
                              hipStream_t stream) {
  const float* hs   = (const float*)d_in[0];
  const float* w    = (const float*)d_in[1];
  const float* bias = (const float*)d_in[2];
  float* out        = (float*)d_out;

  const int T = in_sizes[0] / HID;   // 16384
  const int blocks = T / TT;         // 256

  hipLaunchKernelGGL(router_gemm, dim3(blocks), dim3(THREADS), 0, stream,
                     hs, w, bias, out, T);
}

// Round 7
// 69.018 us; speedup vs baseline: 41.8889x; 1.2938x over previous
//
#include <hip/hip_runtime.h>
#include <math.h>

#define NE 32
#define HID 2880
#define TT 128           // tokens per block (two 64-row halves share W reads)
#define THREADS 512      // 8 waves = 2 (expert-half) x 4 (k-slice)
#define CK 48            // k-chunk staged in LDS
#define NCHUNK 15        // 720 / 48 per k-quarter
#define KQ 4             // k-quarters across blocks
#define KQLEN 720

// global_load_lds: wave-uniform LDS dest + lane*16; per-lane global src.
#define GLL(gsrc, ldst)                                                        \
  __builtin_amdgcn_global_load_lds(                                            \
      (const __attribute__((address_space(1))) unsigned int*)(gsrc),           \
      (__attribute__((address_space(3))) unsigned int*)(ldst), 16, 0, 0)

// Swizzled slot for col-group x (0..11) of row r. XOR involution; slots 0-7
// get full 3-bit spread, slots 8-11 a 2-bit spread (12 slots/row isn't pow2).
__device__ __forceinline__ int swz(int x, int r) {
  return (x < 8) ? (x ^ (r & 7)) : (8 + ((x & 3) ^ (r & 3)));
}

__global__ void __launch_bounds__(THREADS, 4) router_part(
    const float* __restrict__ hs,   // [T][HID]
    const float* __restrict__ w,    // [NE][HID]
    float* __restrict__ wsp,        // [KQ][T][NE] partial logits
    int T)
{
  __shared__ float hbuf[2][TT * CK];   // 2 x 24576 B
  __shared__ float wbuf[2][NE * CK];   // 2 x  6144 B  -> 61440 B (2 blocks/CU)
  float* const part = &hbuf[0][0];     // [2][TT][20] overlay after the loop

  const int tid  = threadIdx.x;
  const int wv   = __builtin_amdgcn_readfirstlane(tid >> 6);
  const int lane = tid & 63;
  const int eg   = wv >> 2;            // experts [eg*16, +16)
  const int kg   = wv & 3;             // k-slice [kg*12, +12) within chunk
  const int ntg  = T / TT;             // 128
  const int tg   = blockIdx.x % ntg;
  const int kq   = blockIdx.x / ntg;   // k-quarter 0..3
  const int t0   = tg * TT;
  const int k0   = kq * KQLEN;

  // ---- staging offsets: h slot f <- h[f/12][ swz(f%12, row)*4 .. ] ----
  int goffH[3];
#pragma unroll
  for (int i = 0; i < 3; ++i) {
    int f   = tid + THREADS * i;       // 0..1535
    int row = f / 12;
    int s   = f % 12;
    goffH[i] = row * HID + swz(s, row) * 4;   // float offset within chunk
  }
  // W slot f (f<384, waves 0..5) <- w[f/12][(f%12)*4 ..] (linear: broadcast)
  const int goffW = (tid / 12) * HID + (tid % 12) * 4;

  float accA[16], accB[16];
#pragma unroll
  for (int i = 0; i < 16; ++i) { accA[i] = 0.f; accB[i] = 0.f; }

  // ---- prologue: stage chunk 0 ----
  {
    const float* hsrc = hs + (size_t)t0 * HID + k0;
#pragma unroll
    for (int i = 0; i < 3; ++i)
      GLL(hsrc + goffH[i], (char*)&hbuf[0][0] + (tid + THREADS * i) * 16);
    if (wv < 6) GLL(w + k0 + goffW, (char*)&wbuf[0][0] + tid * 16);
  }
  __syncthreads();   // compiler drains vmcnt before s_barrier

#pragma clang loop unroll(disable)
  for (int c = 0; c < NCHUNK; ++c) {
    const float* hb_c = &hbuf[c & 1][0];
    const float* wb_c = &wbuf[c & 1][0];

    // issue next chunk's staging (async; lands before next barrier's drain)
    if (c + 1 < NCHUNK) {
      char* hb_n = (char*)&hbuf[(c + 1) & 1][0];
      char* wb_n = (char*)&wbuf[(c + 1) & 1][0];
      const float* hsrc = hs + (size_t)t0 * HID + k0 + (c + 1) * CK;
#pragma unroll
      for (int i = 0; i < 3; ++i)
        GLL(hsrc + goffH[i], hb_n + (tid + THREADS * i) * 16);
      if (wv < 6) GLL(w + k0 + (c + 1) * CK + goffW, wb_n + tid * 16);
    }

    // ---- h fragments for both token halves (same swz: (64+lane)&7==lane&7)
    float hA[12], hB[12];
    const float* baseA = hb_c + lane * CK;
    const float* baseB = hb_c + (64 + lane) * CK;
#pragma unroll
    for (int j = 0; j < 3; ++j) {
      int off = 4 * swz(kg * 3 + j, lane);
      float4 a = *(const float4*)(baseA + off);
      float4 b = *(const float4*)(baseB + off);
      hA[j*4+0]=a.x; hA[j*4+1]=a.y; hA[j*4+2]=a.z; hA[j*4+3]=a.w;
      hB[j*4+0]=b.x; hB[j*4+1]=b.y; hB[j*4+2]=b.z; hB[j*4+3]=b.w;
    }

    // ---- 16 experts: each W b128 broadcast feeds 8 FMAs (A+B halves) ----
    const float* wub = wb_c + eg * (16 * CK) + kg * 12;
#pragma unroll
    for (int e = 0; e < 16; ++e) {
      float4 w0 = *(const float4*)(wub + e * CK);
      float4 w1 = *(const float4*)(wub + e * CK + 4);
      float4 w2 = *(const float4*)(wub + e * CK + 8);
      float ta = accA[e], tb = accB[e];
      ta = fmaf(hA[0], w0.x, ta);  tb = fmaf(hB[0], w0.x, tb);
      ta = fmaf(hA[1], w0.y, ta);  tb = fmaf(hB[1], w0.y, tb);
      ta = fmaf(hA[2], w0.z, ta);  tb = fmaf(hB[2], w0.z, tb);
      ta = fmaf(hA[3], w0.w, ta);  tb = fmaf(hB[3], w0.w, tb);
      ta = fmaf(hA[4], w1.x, ta);  tb = fmaf(hB[4], w1.x, tb);
      ta = fmaf(hA[5], w1.y, ta);  tb = fmaf(hB[5], w1.y, tb);
      ta = fmaf(hA[6], w1.z, ta);  tb = fmaf(hB[6], w1.z, tb);
      ta = fmaf(hA[7], w1.w, ta);  tb = fmaf(hB[7], w1.w, tb);
      ta = fmaf(hA[8], w2.x, ta);  tb = fmaf(hB[8], w2.x, tb);
      ta = fmaf(hA[9], w2.y, ta);  tb = fmaf(hB[9], w2.y, tb);
      ta = fmaf(hA[10], w2.z, ta); tb = fmaf(hB[10], w2.z, tb);
      ta = fmaf(hA[11], w2.w, ta); tb = fmaf(hB[11], w2.w, tb);
      accA[e] = ta; accB[e] = tb;
    }

    __syncthreads();  // readers done with c; vmcnt drained (c+1 staged)
  }

  // ---- reduce 4 kg-waves into part[eg][row][20] overlay (stride 20:
  //      phase 5*row+q sweeps all 8 16B-slots -> conflict-free-ish) ----
#pragma unroll
  for (int ph = 0; ph < 4; ++ph) {
    if (kg == ph) {
#pragma unroll
      for (int half = 0; half < 2; ++half) {
        const float* a = half ? accB : accA;
        int row = half * 64 + lane;
        float* pp = part + (eg * TT + row) * 20;
        if (ph == 0) {
#pragma unroll
          for (int q = 0; q < 4; ++q) {
            float4 v;
            v.x = a[q*4+0]; v.y = a[q*4+1]; v.z = a[q*4+2]; v.w = a[q*4+3];
            *(float4*)(pp + q * 4) = v;
          }
        } else {
#pragma unroll
          for (int q = 0; q < 4; ++q) {
            float4 v = *(float4*)(pp + q * 4);
            v.x += a[q*4+0]; v.y += a[q*4+1]; v.z += a[q*4+2]; v.w += a[q*4+3];
            *(float4*)(pp + q * 4) = v;
          }
        }
      }
    }
    __syncthreads();
  }

  // ---- write partial logits: [kq][t0+tok][32], coalesced float4 ----
  float* dst = wsp + ((size_t)kq * T + t0) * NE;
#pragma unroll
  for (int i = 0; i < 2; ++i) {
    int idx = tid + THREADS * i;        // 0..1023 float4 slots
    int tok = idx >> 3;
    int g   = idx & 7;                  // which float4 of the 32 floats
    float4 v = *(float4*)(part + ((g >> 2) * TT + tok) * 20 + (g & 3) * 4);
    *(float4*)(dst + tok * NE + g * 4) = v;
  }
}

__global__ void __launch_bounds__(128) router_topk(
    const float* __restrict__ wsp,  // [KQ][T][NE]
    const float* __restrict__ bias, // [NE]
    float* __restrict__ out,        // [T][NE] scores, then [T][4] idx-as-float
    int T)
{
  const int tok = blockIdx.x * 128 + threadIdx.x;

  float lg[NE];
#pragma unroll
  for (int e = 0; e < NE; e += 4) {
    float4 bb = *(const float4*)(bias + e);
    lg[e] = bb.x; lg[e+1] = bb.y; lg[e+2] = bb.z; lg[e+3] = bb.w;
  }
#pragma unroll
  for (int q = 0; q < KQ; ++q) {
    const float* p = wsp + ((size_t)q * T + tok) * NE;
#pragma unroll
    for (int e = 0; e < NE; e += 4) {
      float4 v = *(const float4*)(p + e);
      lg[e] += v.x; lg[e+1] += v.y; lg[e+2] += v.z; lg[e+3] += v.w;
    }
  }

  float tv[4]; int ti[4];
#pragma unroll
  for (int kk = 0; kk < 4; ++kk) {
    float m = -INFINITY; int mi = 0;
#pragma unroll
    for (int e = 0; e < NE; ++e) {
      bool gt = lg[e] > m;        // strict >: lowest index wins ties (jax)
      m  = gt ? lg[e] : m;
      mi = gt ? e : mi;
    }
    tv[kk] = m; ti[kk] = mi;
#pragma unroll
    for (int e = 0; e < NE; ++e)
      lg[e] = (e == mi) ? -INFINITY : lg[e];
  }

  float e1 = __expf(tv[1] - tv[0]);
  float e2 = __expf(tv[2] - tv[0]);
  float e3 = __expf(tv[3] - tv[0]);
  float inv = 1.0f / (1.0f + e1 + e2 + e3);
  float pr[4] = {inv, e1 * inv, e2 * inv, e3 * inv};

  float* orow = out + (size_t)tok * NE;
#pragma unroll
  for (int g = 0; g < 8; ++g) {
    float4 v;
    float* vp = (float*)&v;
#pragma unroll
    for (int cb = 0; cb < 4; ++cb) {
      int e = g * 4 + cb;
      float x = 0.f;
      x = (e == ti[0]) ? pr[0] : x;
      x = (e == ti[1]) ? pr[1] : x;
      x = (e == ti[2]) ? pr[2] : x;
      x = (e == ti[3]) ? pr[3] : x;
      vp[cb] = x;
    }
    *(float4*)(orow + g * 4) = v;
  }
  float* oidx = out + (size_t)T * NE + (size_t)tok * 4;
  float4 iv;
  iv.x = (float)ti[0]; iv.y = (float)ti[1]; iv.z = (float)ti[2]; iv.w = (float)ti[3];
  *(float4*)oidx = iv;
}

extern "C" void kernel_launch(void* const* d_in, const int* in_sizes, int n_in,
                              void* d_out, int out_size, void* d_ws, size_t ws_size,
                              hipStream_t stream) {
  const float* hs   = (const float*)d_in[0];
  const float* w    = (const float*)d_in[1];
  const float* bias = (const float*)d_in[2];
  float* out        = (float*)d_out;
  float* wsp        = (float*)d_ws;   // needs KQ*T*NE*4 = 8 MiB

  const int T = in_sizes[0] / HID;    // 16384
  const int ntg = T / TT;             // 128

  hipLaunchKernelGGL(router_part, dim3(ntg * KQ), dim3(THREADS), 0, stream,
                     hs, w, wsp, T);
  hipLaunchKernelGGL(router_topk, dim3(T / 128), dim3(128), 0, stream,
                     wsp, bias, out, T);
}